// Round 10
// baseline (114.593 us; speedup 1.0000x reference)
//
#include <hip/hip_runtime.h>
#include <math.h>

// Problem constants (fixed shapes from setup_inputs)
#define BI 128
#define BT 128
#define RR 36
#define WW 50
#define DD 256
#define EPSF 1e-6f
// exp((s-1)/0.05) = exp2(s*C1 + C0), C1 = 20*log2(e), C0 = -C1
#define EXP2_C1 28.85390081777927f
#define EXP2_C0 (-28.85390081777927f)

#define A_TILES 3        // ceil(36/16)
#define B_TILES 4        // ceil(50/16)
#define KSTEPS 8         // 256 / 32
#define A_SLOTS (BI * A_TILES * KSTEPS * 64)  // 196608 slots x 16B = 3 MiB
#define B_SLOTS (BT * B_TILES * KSTEPS * 64)  // 262144 slots x 16B = 4 MiB
// d_ws layout: [Ah | Bh] (f16 fragments) = 3+4 MiB = 7,340,032 bytes

#define AVROWS (BI * 48)          // 6144 virtual A rows (pad to 3 tiles)
#define NVROWS (AVROWS + BT * 64) // + 8192 virtual B rows = 14336

typedef short     v8ss __attribute__((ext_vector_type(8)));
typedef _Float16  v8hf __attribute__((ext_vector_type(8)));
typedef _Float16  v4hf __attribute__((ext_vector_type(4)));
typedef float     v4f  __attribute__((ext_vector_type(4)));

// MFMA shim: tolerate either builtin operand type (v8 half or v8 short).
template <typename V>
__device__ __forceinline__ auto mfma_impl(V a, V b, v4f c, int)
    -> decltype(__builtin_amdgcn_mfma_f32_16x16x32_f16(a, b, c, 0, 0, 0)) {
    return __builtin_amdgcn_mfma_f32_16x16x32_f16(a, b, c, 0, 0, 0);
}
template <typename V>
__device__ __forceinline__ v4f mfma_impl(V a, V b, v4f c, long) {
    v8ss a2 = __builtin_bit_cast(v8ss, a);
    v8ss b2 = __builtin_bit_cast(v8ss, b);
    return __builtin_amdgcn_mfma_f32_16x16x32_f16(a2, b2, c, 0, 0, 0);
}
__device__ __forceinline__ v4f mfma_f16(v8hf a, v8hf b, v4f c) {
    return mfma_impl(a, b, c, 0);
}

__device__ __forceinline__ float fast_rcp(float x) {
    return __builtin_amdgcn_rcpf(x);
}
__device__ __forceinline__ float fast_exp2(float x) {
    return __builtin_amdgcn_exp2f(x);
}

// DPP row_ror-based sum over each aligned 16-lane group (all lanes get sum)
template <int N>
__device__ __forceinline__ float dpp_ror_add(float x) {
    int xi = __builtin_bit_cast(int, x);
    int yi = __builtin_amdgcn_update_dpp(xi, xi, 0x120 | N, 0xF, 0xF, false);
    return x + __builtin_bit_cast(float, yi);
}
__device__ __forceinline__ float dpp_sum16(float x) {
    x = dpp_ror_add<1>(x);
    x = dpp_ror_add<2>(x);
    x = dpp_ror_add<4>(x);
    x = dpp_ror_add<8>(x);
    return x;
}

// ---------------------------------------------------------------------------
// Kernel 1 (v2): ONE WAVE PER VIRTUAL ROW, no LDS, no barriers.
// Lane l loads float4 l of the row (perfectly coalesced, 1KB per wave),
// 6 xor-shuffles give the full-row sum of squares, then each lane converts
// its own 4 floats to f16 and stores 8B at its fragment position:
//   slot = (tile_base + ks)*64 + rr + kq*16, half = lane&1
//   where ks = lane>>3, kq = (lane>>1)&3  (lane owns k = 4*lane .. 4*lane+3).
// Pad rows write zeros so poisoned d_ws is fully initialized.
// ---------------------------------------------------------------------------
__global__ __launch_bounds__(256) void convert_kernel(
    const float* __restrict__ imgs, const float* __restrict__ caps,
    v8ss* __restrict__ Ah_g, v8ss* __restrict__ Bh_g)
{
    const int gid  = blockIdx.x * 256 + threadIdx.x;
    const int wv   = gid >> 6;
    const int lane = gid & 63;

    const bool isA = wv < AVROWS;
    int grp, r, nrows;
    const float* src;
    v8ss* dst;
    size_t tbase;
    if (isA) {
        grp = wv / 48; r = wv - grp * 48;
        src = imgs + ((size_t)grp * RR + r) * DD;
        nrows = RR; dst = Ah_g;
        tbase = (size_t)(grp * A_TILES + (r >> 4)) * KSTEPS;
    } else {
        const int v = wv - AVROWS;
        grp = v >> 6; r = v & 63;
        src = caps + ((size_t)grp * WW + r) * DD;
        nrows = WW; dst = Bh_g;
        tbase = (size_t)(grp * B_TILES + (r >> 4)) * KSTEPS;
    }
    const bool valid = r < nrows;

    float4 x = make_float4(0.f, 0.f, 0.f, 0.f);
    if (valid) x = ((const float4*)src)[lane];
    float ss = x.x * x.x + x.y * x.y + x.z * x.z + x.w * x.w;
#pragma unroll
    for (int off = 1; off < 64; off <<= 1) ss += __shfl_xor(ss, off, 64);
    const float inv = valid ? 1.0f / fmaxf(sqrtf(ss), 1e-8f) : 0.f;

    v4hf h;
    h[0] = (_Float16)(x.x * inv);
    h[1] = (_Float16)(x.y * inv);
    h[2] = (_Float16)(x.z * inv);
    h[3] = (_Float16)(x.w * inv);

    const int rr = r & 15;
    const int ks = lane >> 3;
    const int kq = (lane >> 1) & 3;
    const size_t slot = (tbase + ks) * 64 + rr + (kq << 4);
    ((uint2*)dst)[slot * 2 + (lane & 1)] = __builtin_bit_cast(uint2, h);
}

// ---------------------------------------------------------------------------
// Kernel 2 (v3): block = 256 thr = 4 waves = ONE j, FOUR i (i = ig + 32w).
// Prologue: B_j fragments (Na*8 KB <= 32 KB) staged into LDS ONCE, shared by
// all 4 waves -> B global traffic /4 and B load latency becomes ds_read_b128.
// K-loop per wave: A from global (register ping-pong, L2-hot via XCD swizzle),
// B from LDS (ping-pong). Single-pass f16 MFMA, tiles pruned by lengths.
// XCD swizzle: xcd = blockIdx&7 owns j-slice [16x,16x+16) -> per-XCD L2 holds
// 512 KB B-slice + 3 MB A (fits 4 MB).
// Regs ~115 (ah 24 + bh 32 + acc 48 AGPR + misc) -> 4 waves/SIMD at (256,4).
// Sinkhorn via u/v factorization, all in registers (as R9).
// C/D layout: col = lane&15, row = (lane>>4)*4 + reg.
// ---------------------------------------------------------------------------
__global__ __launch_bounds__(256, 4) void pair_kernel(
    const v8ss* __restrict__ Ah_g, const v8ss* __restrict__ Bh_g,
    const int* __restrict__ img_lens, const int* __restrict__ cap_lens,
    float* __restrict__ out)
{
    __shared__ v8ss Bs[B_TILES * KSTEPS * 64];   // 32 KB

    const int tid  = threadIdx.x;
    const int lane = tid & 63;
    const int w    = tid >> 6;                   // wave 0..3
    const int x    = blockIdx.x & 7;             // XCD id (round-robin)
    const int jg   = (blockIdx.x >> 3) & 15;
    const int ig   = blockIdx.x >> 7;            // 0..31
    const int j    = (x << 4) + jg;              // block-uniform
    const int i    = ig + (w << 5);              // wave-uniform

    const int nc = cap_lens[j];
    const int Na = (nc + 15) >> 4;
    const int nr = img_lens[i];
    const int Ma = (nr + 15) >> 4;

    // ---- stage B_j into LDS (coalesced, Na*512 slots of 16B) ----
    {
        const v8ss* Bj = Bh_g + (size_t)j * (B_TILES * KSTEPS * 64);
        const int nslot = Na * (KSTEPS * 64);
        for (int s = tid; s < nslot; s += 256) Bs[s] = Bj[s];
    }
    __syncthreads();

    const v8ss* Ah_b = Ah_g + (size_t)i * (A_TILES * KSTEPS * 64) + lane;

    v4f acc[3][4];
#pragma unroll
    for (int m = 0; m < 3; ++m)
#pragma unroll
        for (int n = 0; n < 4; ++n) acc[m][n] = (v4f){0.f, 0.f, 0.f, 0.f};

    v8hf ah[2][3], bh[2][4];
    auto load_A = [&](int ks, int buf) {
#pragma unroll
        for (int m = 0; m < 3; ++m) if (m < Ma)
            ah[buf][m] = __builtin_bit_cast(v8hf, Ah_b[(m * KSTEPS + ks) * 64]);
    };
    auto read_B = [&](int ks, int buf) {
#pragma unroll
        for (int n = 0; n < 4; ++n) if (n < Na)
            bh[buf][n] = __builtin_bit_cast(v8hf, Bs[(n * KSTEPS + ks) * 64 + lane]);
    };

    load_A(0, 0);
    read_B(0, 0);
#pragma unroll
    for (int ks = 0; ks < KSTEPS; ++ks) {
        const int cur = ks & 1;
        if (ks + 1 < KSTEPS) {
            load_A(ks + 1, cur ^ 1);
            read_B(ks + 1, cur ^ 1);
        }
#pragma unroll
        for (int n = 0; n < 4; ++n) if (n < Na)
#pragma unroll
            for (int m = 0; m < 3; ++m) if (m < Ma)
                acc[m][n] = mfma_f16(ah[cur][m], bh[cur][n], acc[m][n]);
    }

    // ---- Sinkhorn via u/v factorization (all wave-local registers) ----
    const int cl = lane & 15;
    const int rq = (lane >> 4) << 2;
    const float inv_nr = 1.0f / (float)nr;
    const float inv_nc = 1.0f / (float)nc;

    float P0[3][4][4];
    float tot = 0.f;
#pragma unroll
    for (int m = 0; m < 3; ++m) if (m < Ma)
#pragma unroll
        for (int n = 0; n < 4; ++n) if (n < Na)
#pragma unroll
            for (int q = 0; q < 4; ++q) {
                const int row = (m << 4) + rq + q;
                const int col = (n << 4) + cl;
                float pv = 0.f;
                if (row < nr && col < nc)
                    pv = fast_exp2(fmaf(acc[m][n][q], EXP2_C1, EXP2_C0));
                P0[m][n][q] = pv;
                tot += pv;
            }
    tot = dpp_sum16(tot);
    tot += __shfl_xor(tot, 16, 64);
    tot += __shfl_xor(tot, 32, 64);
    const float gsc = fast_rcp(tot + EPSF);

    float u[3][4], v[4];
#pragma unroll
    for (int m = 0; m < 3; ++m)
#pragma unroll
        for (int q = 0; q < 4; ++q) u[m][q] = gsc;   // rows with P0=0 harmless
#pragma unroll
    for (int n = 0; n < 4; ++n) v[n] = 1.0f;

#pragma unroll
    for (int it = 0; it < 3; ++it) {
        // row update: t = u[r]*sum_c(P0*v); u *= (1/nr)*rcp(t+EPS)
#pragma unroll
        for (int m = 0; m < 3; ++m) if (m < Ma)
#pragma unroll
            for (int q = 0; q < 4; ++q) {
                float d = 0.f;
#pragma unroll
                for (int n = 0; n < 4; ++n) if (n < Na)
                    d = fmaf(P0[m][n][q], v[n], d);
                d = dpp_sum16(d);
                const float t = fmaf(u[m][q], d, EPSF);
                u[m][q] *= inv_nr * fast_rcp(t);
            }
        // col update: t = v[c]*sum_r(P0*u); v *= (1/nc)*rcp(t+EPS)
#pragma unroll
        for (int n = 0; n < 4; ++n) if (n < Na) {
            float e = 0.f;
#pragma unroll
            for (int m = 0; m < 3; ++m) if (m < Ma)
#pragma unroll
                for (int q = 0; q < 4; ++q)
                    e = fmaf(P0[m][n][q], u[m][q], e);
            e += __shfl_xor(e, 16, 64);
            e += __shfl_xor(e, 32, 64);
            const float t = fmaf(v[n], e, EPSF);
            v[n] *= inv_nc * fast_rcp(t);
        }
    }

    // ---- output: sum(S * P0 * u * v), two accumulators to break the chain ----
    float os0 = 0.f, os1 = 0.f;
#pragma unroll
    for (int m = 0; m < 3; ++m) if (m < Ma)
#pragma unroll
        for (int n = 0; n < 4; ++n) if (n < Na)
#pragma unroll
            for (int q = 0; q < 4; ++q) {
                const float t = P0[m][n][q] * u[m][q] * v[n];
                if (q & 1) os1 = fmaf(acc[m][n][q], t, os1);
                else       os0 = fmaf(acc[m][n][q], t, os0);
            }
    float osum = os0 + os1;
    osum = dpp_sum16(osum);
    osum += __shfl_xor(osum, 16, 64);
    osum += __shfl_xor(osum, 32, 64);
    if (lane == 0) out[i * BT + j] = osum;
}

extern "C" void kernel_launch(void* const* d_in, const int* in_sizes, int n_in,
                              void* d_out, int out_size, void* d_ws, size_t ws_size,
                              hipStream_t stream) {
    const float* imgs     = (const float*)d_in[0];
    const float* caps     = (const float*)d_in[1];
    const int*   img_lens = (const int*)d_in[2];
    const int*   cap_lens = (const int*)d_in[3];
    float* out = (float*)d_out;

    // workspace layout (7,340,032 bytes total)
    v8ss* Ah_g = (v8ss*)d_ws;
    v8ss* Bh_g = Ah_g + A_SLOTS;

    // 14336 waves, one per virtual row -> 3584 blocks
    hipLaunchKernelGGL(convert_kernel, dim3(NVROWS * 64 / 256), dim3(256), 0, stream,
                       imgs, caps, Ah_g, Bh_g);
    // 4096 blocks x 4 waves = 16384 pairs (one j, four i per block)
    hipLaunchKernelGGL(pair_kernel, dim3(BI * BT / 4), dim3(256), 0, stream,
                       Ah_g, Bh_g, img_lens, cap_lens, out);
}